// Round 12
// baseline (144.883 us; speedup 1.0000x reference)
//
#include <hip/hip_runtime.h>
#include <hip/hip_bf16.h>

// InfoNCE loss, N=4096, D=1024, TEMP=0.07.
// loss = mean_i( -pos_i + lse_i ), lse over sim rows with diagonal masked.
// Fixed-max LSE (rows unit-norm -> sim <= 1/T): partials are order-independent.
// Symmetry via 128x128 tiles, upper triangle (J >= I).
//
// R12: R11 with the LDS sizing bug FIXED (R11 overlapped its two buffers and
// wrote OOB -> racy absmax 0.0625). SLOT = 8192 shorts = 16 KB per slot
// (A 128x32 + B 128x32), double-buffer = 32 KiB, cur/oth fully disjoint.
// __launch_bounds__(256,5): 5 blocks x 32 KiB = 160 KiB LDS exactly,
// VGPR target 102 >> 56 used. Counted vmcnt(4) gate, 2 barriers/step,
// zero-conflict XOR swizzle, plane-store epilogue, Ji-bounded reduce.

typedef __attribute__((ext_vector_type(8))) short bf16x8;
typedef __attribute__((ext_vector_type(4))) float f32x4;

#define NN 4096
#define TWO_N 8192
#define DIM 1024
#define TEMP_INV 14.285714285714286f
#define EXP_SCALE 20.609929155566303f /* log2(e)/0.07 */
#define NT 64     /* tiles of 128 per dim */
#define NBLK 2080 /* 64*65/2 upper-tri tiles; 2080 % 8 == 0 -> bijective */
#define SLOT 8192 /* shorts per slot: A[128][32] + B[128][32] = 16 KB */

#define GLD16(g, l)                                                          \
  __builtin_amdgcn_global_load_lds(                                          \
      (const __attribute__((address_space(1))) void*)(g),                    \
      (__attribute__((address_space(3))) void*)(l), 16, 0, 0)

__device__ __forceinline__ unsigned short f2bf(float f) {
  unsigned int u = __float_as_uint(f);
  u += 0x7fffu + ((u >> 16) & 1u);  // RNE
  return (unsigned short)(u >> 16);
}

// Fused: fp32->bf16 cast of z=[z1;z2] AND pos[row]=dot(z1,z2)/T (one 32MB read).
__global__ __launch_bounds__(256) void prep_kernel(
    const float* __restrict__ z1, const float* __restrict__ z2,
    unsigned short* __restrict__ zb, float* __restrict__ pos) {
  const int row = blockIdx.x, t = threadIdx.x;
  float4 a = ((const float4*)(z1 + (size_t)row * DIM))[t];
  float4 b = ((const float4*)(z2 + (size_t)row * DIM))[t];
  ushort4 ua = {f2bf(a.x), f2bf(a.y), f2bf(a.z), f2bf(a.w)};
  ushort4 ub = {f2bf(b.x), f2bf(b.y), f2bf(b.z), f2bf(b.w)};
  ((ushort4*)(zb + (size_t)row * DIM))[t] = ua;
  ((ushort4*)(zb + (size_t)(NN + row) * DIM))[t] = ub;
  float s = a.x * b.x + a.y * b.y + a.z * b.z + a.w * b.w;
#pragma unroll
  for (int off = 1; off < 64; off <<= 1) s += __shfl_xor(s, off);
  __shared__ float tmp[4];
  if ((t & 63) == 0) tmp[t >> 6] = s;
  __syncthreads();
  if (t == 0) pos[row] = (tmp[0] + tmp[1] + tmp[2] + tmp[3]) * TEMP_INV;
}

__global__ __launch_bounds__(256, 5) void lse_kernel(
    const unsigned short* __restrict__ zb, float* __restrict__ part) {
  __shared__ unsigned short lds[2 * SLOT];  // 32 KiB; 5 blocks/CU = 160 KiB
  // ---- tile decode: XCD swizzle -> upper-tri (I, J), J >= I ----
  int u = ((int)blockIdx.x & 7) * (NBLK / 8) + ((int)blockIdx.x >> 3);
  int I = 0, rem = u;
  while (rem >= NT - I) { rem -= NT - I; ++I; }
  const int J = I + rem;
  const int rowA0 = I * 128, colB0 = J * 128;
  const bool diag = (I == J);

  const int t = threadIdx.x;
  const int wave = t >> 6, lane = t & 63;
  const int wm = wave >> 1, wn = wave & 1;  // 2x2 waves, each 64x64 out
  const int lo = lane & 15, hi = lane >> 4;

  // ---- staging: 2 A-chunks + 2 B-chunks (16B each) per thread per slot ----
  // slot layout (shorts): A[128 rows][32] at 0, B[128][32] at 4096. Chunk c
  // (16B): row=c>>2, phys group p=c&3 holds logical lg = p ^ ((row>>1)&3)
  // (inverse of the read-side XOR). LDS dest linear (wave-uniform + lane*16).
  int oA[2], oB[2];
#pragma unroll
  for (int i = 0; i < 2; ++i) {
    int c = i * 256 + wave * 64 + lane, row = c >> 2, p = c & 3;
    oA[i] = (rowA0 + row) * DIM + (p ^ ((row >> 1) & 3)) * 8;
    oB[i] = (colB0 + row) * DIM + (p ^ ((row >> 1) & 3)) * 8;
  }

  // ---- compute-side ds_read offsets (shorts), swizzle applied on read ----
  const int sx = (hi ^ ((lo >> 1) & 3)) * 8;  // swizzled 16B group
  const int arow0 = wm * 64 + lo;             // + m*16
  const int brow0 = wn * 64 + lo;             // + n*16

  f32x4 acc[4][4];
#pragma unroll
  for (int m = 0; m < 4; ++m)
#pragma unroll
    for (int n = 0; n < 4; ++n) acc[m][n] = (f32x4){0.f, 0.f, 0.f, 0.f};

#define STAGE(dst_, k_)                                                       \
  {                                                                           \
    const unsigned short* gk = zb + (size_t)((k_) & 31) * 32;                 \
    GLD16(gk + oA[0], (dst_) + wave * 512);                                   \
    GLD16(gk + oA[1], (dst_) + 2048 + wave * 512);                            \
    GLD16(gk + oB[0], (dst_) + 4096 + wave * 512);                            \
    GLD16(gk + oB[1], (dst_) + 4096 + 2048 + wave * 512);                     \
  }

  unsigned short* cur = lds;         // slot holding tile s
  unsigned short* oth = lds + SLOT;  // slot holding tile s+1 (stage target)

  STAGE(cur, 0);
  asm volatile("s_waitcnt vmcnt(0)" ::: "memory");  // own slot-0 loads done

#pragma unroll 1
  for (int s = 0; s < DIM / 32; ++s) {
    __builtin_amdgcn_s_barrier();  // BAR_A: all waves done reading oth (s-1)
    __builtin_amdgcn_sched_barrier(0);
    STAGE(oth, s + 1);             // s=31: dummy wrap (k&31=0), never read
    asm volatile("s_waitcnt vmcnt(4)" ::: "memory");  // own slot-s loads done
    __builtin_amdgcn_s_barrier();  // BAR_B: slot s published across waves
    __builtin_amdgcn_sched_barrier(0);

    bf16x8 bg[4];
#pragma unroll
    for (int n = 0; n < 4; ++n)
      bg[n] = *(const bf16x8*)(cur + 4096 + (brow0 + n * 16) * 32 + sx);
    __builtin_amdgcn_s_setprio(1);
#pragma unroll
    for (int m = 0; m < 4; ++m) {
      bf16x8 af = *(const bf16x8*)(cur + (arow0 + m * 16) * 32 + sx);
#pragma unroll
      for (int n = 0; n < 4; ++n)
        acc[m][n] = __builtin_amdgcn_mfma_f32_16x16x32_bf16(af, bg[n], acc[m][n], 0, 0, 0);
    }
    __builtin_amdgcn_s_setprio(0);
    unsigned short* tmp_ = cur; cur = oth; oth = tmp_;  // swap buffers
  }
  asm volatile("s_waitcnt vmcnt(0) lgkmcnt(0)" ::: "memory");  // drain dummy

  // ---- epilogue: e=exp((dot-1)/T), diag masked; row/col partial sums ----
  // NO atomics: plain stores to tile-private planes (row partials keyed
  // (J,wn) -> planes 0..127; col partials keyed (I,wm) -> planes 128..255).
  float* rplane = part + (size_t)(2 * J + wn) * TWO_N;
  float* cplane = part + (size_t)(128 + 2 * I + wm) * TWO_N;
  float csum[4] = {0.f, 0.f, 0.f, 0.f};
#pragma unroll
  for (int m = 0; m < 4; ++m) {
#pragma unroll
    for (int r = 0; r < 4; ++r) {
      const int grow = rowA0 + wm * 64 + m * 16 + hi * 4 + r;  // row=(lane>>4)*4+reg
      float s = 0.f;
#pragma unroll
      for (int n = 0; n < 4; ++n) {
        const int gcol = colB0 + wn * 64 + n * 16 + lo;        // col=lane&15
        float e = exp2f((acc[m][n][r] - 1.0f) * EXP_SCALE);
        if (grow == gcol) e = 0.f;  // mask self-similarity (diag tiles)
        s += e;
        csum[n] += e;
      }
      s += __shfl_xor(s, 1); s += __shfl_xor(s, 2);
      s += __shfl_xor(s, 4); s += __shfl_xor(s, 8);
      if (lo == 0) rplane[grow] = s;  // 4 lanes, 64 distinct rows per wave
    }
  }
  if (!diag) {  // off-diagonal tiles feed transposed rows via col sums
#pragma unroll
    for (int n = 0; n < 4; ++n) {
      float s = csum[n];
      s += __shfl_xor(s, 16); s += __shfl_xor(s, 32);
      if (hi == 0) cplane[colB0 + wn * 64 + n * 16 + lo] = s;  // 16 lanes
    }
  }
#undef STAGE
}

// Fold only the provably-written plane entries -> per-row term -> mean.
// For row i (Ji = i>>7): row-planes 2J+{0,1} are written iff J >= Ji;
// col-planes 128+2I+{0,1} iff I < Ji. Exactly 128 entries per row, so no
// workspace memset is needed (stale bytes are never read).
__global__ __launch_bounds__(256) void reduce_finalize_kernel(
    const float* __restrict__ part, const float* __restrict__ pos,
    float* __restrict__ out) {
  const int i = blockIdx.x * 256 + threadIdx.x;
  const int Ji = i >> 7;
  float s = 0.f;
  for (int J = Ji; J < NT; ++J)
    s += part[(size_t)(2 * J) * TWO_N + i] + part[(size_t)(2 * J + 1) * TWO_N + i];
  for (int I = 0; I < Ji; ++I)
    s += part[(size_t)(128 + 2 * I) * TWO_N + i] +
         part[(size_t)(128 + 2 * I + 1) * TWO_N + i];
  float term = TEMP_INV + logf(s) - pos[i & (NN - 1)];
#pragma unroll
  for (int off = 1; off < 64; off <<= 1) term += __shfl_xor(term, off);
  __shared__ float tmp[4];
  const int t = threadIdx.x;
  if ((t & 63) == 0) tmp[t >> 6] = term;
  __syncthreads();
  if (t == 0)
    atomicAdd(out, (tmp[0] + tmp[1] + tmp[2] + tmp[3]) * (1.0f / (float)TWO_N));
}

extern "C" void kernel_launch(void* const* d_in, const int* in_sizes, int n_in,
                              void* d_out, int out_size, void* d_ws, size_t ws_size,
                              hipStream_t stream) {
  const float* z1 = (const float*)d_in[0];
  const float* z2 = (const float*)d_in[1];
  float* out = (float*)d_out;

  char* ws = (char*)d_ws;
  unsigned short* zb = (unsigned short*)ws;            // 16 MB bf16 z
  size_t off = (size_t)TWO_N * DIM * 2;
  float* part = (float*)(ws + off);                    // 8 MB: 256 x 8192 f32
  off += (size_t)256 * TWO_N * 4;
  float* pos = (float*)(ws + off);                     // 16 KB

  hipMemsetAsync(out, 0, sizeof(float), stream);
  prep_kernel<<<NN, 256, 0, stream>>>(z1, z2, zb, pos);
  lse_kernel<<<NBLK, 256, 0, stream>>>(zb, part);
  reduce_finalize_kernel<<<TWO_N / 256, 256, 0, stream>>>(part, pos, out);
}

// Round 13
// 130.969 us; speedup vs baseline: 1.1062x; 1.1062x over previous
//
#include <hip/hip_runtime.h>
#include <hip/hip_bf16.h>

// InfoNCE loss, N=4096, D=1024, TEMP=0.07.
// loss = mean_i( -pos_i + lse_i ), lse over sim rows with diagonal masked.
// Fixed-max LSE (rows unit-norm -> sim <= 1/T): partials are order-independent.
// Symmetry via 128x128 tiles, upper triangle (J >= I).
//
// R13: R12 with __launch_bounds__(256,4) (R12's ask of 5 waves/SIMD capped
// regs at 102 < ~112 needed -> scratch spills, WRITE_SIZE 4->21 MB, regress).
// 4 blocks/CU: reg budget 128 >= 112 (no spill), LDS 4 x 32 KiB = 128 KiB.
// Correct disjoint double-buffer (SLOT=8192 shorts = 16 KB/slot), counted
// vmcnt(4) gate, 2 barriers/step, zero-conflict XOR swizzle, plane-store
// epilogue (no atomics), Ji-bounded reduce (no part memset).

typedef __attribute__((ext_vector_type(8))) short bf16x8;
typedef __attribute__((ext_vector_type(4))) float f32x4;

#define NN 4096
#define TWO_N 8192
#define DIM 1024
#define TEMP_INV 14.285714285714286f
#define EXP_SCALE 20.609929155566303f /* log2(e)/0.07 */
#define NT 64     /* tiles of 128 per dim */
#define NBLK 2080 /* 64*65/2 upper-tri tiles; 2080 % 8 == 0 -> bijective */
#define SLOT 8192 /* shorts per slot: A[128][32] + B[128][32] = 16 KB */

#define GLD16(g, l)                                                          \
  __builtin_amdgcn_global_load_lds(                                          \
      (const __attribute__((address_space(1))) void*)(g),                    \
      (__attribute__((address_space(3))) void*)(l), 16, 0, 0)

__device__ __forceinline__ unsigned short f2bf(float f) {
  unsigned int u = __float_as_uint(f);
  u += 0x7fffu + ((u >> 16) & 1u);  // RNE
  return (unsigned short)(u >> 16);
}

// Fused: fp32->bf16 cast of z=[z1;z2] AND pos[row]=dot(z1,z2)/T (one 32MB read).
__global__ __launch_bounds__(256) void prep_kernel(
    const float* __restrict__ z1, const float* __restrict__ z2,
    unsigned short* __restrict__ zb, float* __restrict__ pos) {
  const int row = blockIdx.x, t = threadIdx.x;
  float4 a = ((const float4*)(z1 + (size_t)row * DIM))[t];
  float4 b = ((const float4*)(z2 + (size_t)row * DIM))[t];
  ushort4 ua = {f2bf(a.x), f2bf(a.y), f2bf(a.z), f2bf(a.w)};
  ushort4 ub = {f2bf(b.x), f2bf(b.y), f2bf(b.z), f2bf(b.w)};
  ((ushort4*)(zb + (size_t)row * DIM))[t] = ua;
  ((ushort4*)(zb + (size_t)(NN + row) * DIM))[t] = ub;
  float s = a.x * b.x + a.y * b.y + a.z * b.z + a.w * b.w;
#pragma unroll
  for (int off = 1; off < 64; off <<= 1) s += __shfl_xor(s, off);
  __shared__ float tmp[4];
  if ((t & 63) == 0) tmp[t >> 6] = s;
  __syncthreads();
  if (t == 0) pos[row] = (tmp[0] + tmp[1] + tmp[2] + tmp[3]) * TEMP_INV;
}

__global__ __launch_bounds__(256, 4) void lse_kernel(
    const unsigned short* __restrict__ zb, float* __restrict__ part) {
  __shared__ unsigned short lds[2 * SLOT];  // 32 KiB; 4 blocks/CU = 128 KiB
  // ---- tile decode: XCD swizzle -> upper-tri (I, J), J >= I ----
  int u = ((int)blockIdx.x & 7) * (NBLK / 8) + ((int)blockIdx.x >> 3);
  int I = 0, rem = u;
  while (rem >= NT - I) { rem -= NT - I; ++I; }
  const int J = I + rem;
  const int rowA0 = I * 128, colB0 = J * 128;
  const bool diag = (I == J);

  const int t = threadIdx.x;
  const int wave = t >> 6, lane = t & 63;
  const int wm = wave >> 1, wn = wave & 1;  // 2x2 waves, each 64x64 out
  const int lo = lane & 15, hi = lane >> 4;

  // ---- staging: 2 A-chunks + 2 B-chunks (16B each) per thread per slot ----
  // slot layout (shorts): A[128 rows][32] at 0, B[128][32] at 4096. Chunk c
  // (16B): row=c>>2, phys group p=c&3 holds logical lg = p ^ ((row>>1)&3)
  // (inverse of the read-side XOR). LDS dest linear (wave-uniform + lane*16).
  int oA[2], oB[2];
#pragma unroll
  for (int i = 0; i < 2; ++i) {
    int c = i * 256 + wave * 64 + lane, row = c >> 2, p = c & 3;
    oA[i] = (rowA0 + row) * DIM + (p ^ ((row >> 1) & 3)) * 8;
    oB[i] = (colB0 + row) * DIM + (p ^ ((row >> 1) & 3)) * 8;
  }

  // ---- compute-side ds_read offsets (shorts), swizzle applied on read ----
  const int sx = (hi ^ ((lo >> 1) & 3)) * 8;  // swizzled 16B group
  const int arow0 = wm * 64 + lo;             // + m*16
  const int brow0 = wn * 64 + lo;             // + n*16

  f32x4 acc[4][4];
#pragma unroll
  for (int m = 0; m < 4; ++m)
#pragma unroll
    for (int n = 0; n < 4; ++n) acc[m][n] = (f32x4){0.f, 0.f, 0.f, 0.f};

#define STAGE(dst_, k_)                                                       \
  {                                                                           \
    const unsigned short* gk = zb + (size_t)((k_) & 31) * 32;                 \
    GLD16(gk + oA[0], (dst_) + wave * 512);                                   \
    GLD16(gk + oA[1], (dst_) + 2048 + wave * 512);                            \
    GLD16(gk + oB[0], (dst_) + 4096 + wave * 512);                            \
    GLD16(gk + oB[1], (dst_) + 4096 + 2048 + wave * 512);                     \
  }

  unsigned short* cur = lds;         // slot holding tile s
  unsigned short* oth = lds + SLOT;  // slot holding tile s+1 (stage target)

  STAGE(cur, 0);
  asm volatile("s_waitcnt vmcnt(0)" ::: "memory");  // own slot-0 loads done

#pragma unroll 1
  for (int s = 0; s < DIM / 32; ++s) {
    __builtin_amdgcn_s_barrier();  // BAR_A: all waves done reading oth (s-1)
    __builtin_amdgcn_sched_barrier(0);
    STAGE(oth, s + 1);             // s=31: dummy wrap (k&31=0), never read
    asm volatile("s_waitcnt vmcnt(4)" ::: "memory");  // own slot-s loads done
    __builtin_amdgcn_s_barrier();  // BAR_B: slot s published across waves
    __builtin_amdgcn_sched_barrier(0);

    bf16x8 bg[4];
#pragma unroll
    for (int n = 0; n < 4; ++n)
      bg[n] = *(const bf16x8*)(cur + 4096 + (brow0 + n * 16) * 32 + sx);
    __builtin_amdgcn_s_setprio(1);
#pragma unroll
    for (int m = 0; m < 4; ++m) {
      bf16x8 af = *(const bf16x8*)(cur + (arow0 + m * 16) * 32 + sx);
#pragma unroll
      for (int n = 0; n < 4; ++n)
        acc[m][n] = __builtin_amdgcn_mfma_f32_16x16x32_bf16(af, bg[n], acc[m][n], 0, 0, 0);
    }
    __builtin_amdgcn_s_setprio(0);
    unsigned short* tmp_ = cur; cur = oth; oth = tmp_;  // swap buffers
  }
  asm volatile("s_waitcnt vmcnt(0) lgkmcnt(0)" ::: "memory");  // drain dummy

  // ---- epilogue: e=exp((dot-1)/T), diag masked; row/col partial sums ----
  // NO atomics: plain stores to tile-private planes (row partials keyed
  // (J,wn) -> planes 0..127; col partials keyed (I,wm) -> planes 128..255).
  float* rplane = part + (size_t)(2 * J + wn) * TWO_N;
  float* cplane = part + (size_t)(128 + 2 * I + wm) * TWO_N;
  float csum[4] = {0.f, 0.f, 0.f, 0.f};
#pragma unroll
  for (int m = 0; m < 4; ++m) {
#pragma unroll
    for (int r = 0; r < 4; ++r) {
      const int grow = rowA0 + wm * 64 + m * 16 + hi * 4 + r;  // row=(lane>>4)*4+reg
      float s = 0.f;
#pragma unroll
      for (int n = 0; n < 4; ++n) {
        const int gcol = colB0 + wn * 64 + n * 16 + lo;        // col=lane&15
        float e = exp2f((acc[m][n][r] - 1.0f) * EXP_SCALE);
        if (grow == gcol) e = 0.f;  // mask self-similarity (diag tiles)
        s += e;
        csum[n] += e;
      }
      s += __shfl_xor(s, 1); s += __shfl_xor(s, 2);
      s += __shfl_xor(s, 4); s += __shfl_xor(s, 8);
      if (lo == 0) rplane[grow] = s;  // 4 lanes, 64 distinct rows per wave
    }
  }
  if (!diag) {  // off-diagonal tiles feed transposed rows via col sums
#pragma unroll
    for (int n = 0; n < 4; ++n) {
      float s = csum[n];
      s += __shfl_xor(s, 16); s += __shfl_xor(s, 32);
      if (hi == 0) cplane[colB0 + wn * 64 + n * 16 + lo] = s;  // 16 lanes
    }
  }
#undef STAGE
}

// Fold only the provably-written plane entries -> per-row term -> mean.
// For row i (Ji = i>>7): row-planes 2J+{0,1} are written iff J >= Ji;
// col-planes 128+2I+{0,1} iff I < Ji. Exactly 128 entries per row, so no
// workspace memset is needed (stale bytes are never read).
__global__ __launch_bounds__(256) void reduce_finalize_kernel(
    const float* __restrict__ part, const float* __restrict__ pos,
    float* __restrict__ out) {
  const int i = blockIdx.x * 256 + threadIdx.x;
  const int Ji = i >> 7;
  float s = 0.f;
  for (int J = Ji; J < NT; ++J)
    s += part[(size_t)(2 * J) * TWO_N + i] + part[(size_t)(2 * J + 1) * TWO_N + i];
  for (int I = 0; I < Ji; ++I)
    s += part[(size_t)(128 + 2 * I) * TWO_N + i] +
         part[(size_t)(128 + 2 * I + 1) * TWO_N + i];
  float term = TEMP_INV + logf(s) - pos[i & (NN - 1)];
#pragma unroll
  for (int off = 1; off < 64; off <<= 1) term += __shfl_xor(term, off);
  __shared__ float tmp[4];
  const int t = threadIdx.x;
  if ((t & 63) == 0) tmp[t >> 6] = term;
  __syncthreads();
  if (t == 0)
    atomicAdd(out, (tmp[0] + tmp[1] + tmp[2] + tmp[3]) * (1.0f / (float)TWO_N));
}

extern "C" void kernel_launch(void* const* d_in, const int* in_sizes, int n_in,
                              void* d_out, int out_size, void* d_ws, size_t ws_size,
                              hipStream_t stream) {
  const float* z1 = (const float*)d_in[0];
  const float* z2 = (const float*)d_in[1];
  float* out = (float*)d_out;

  char* ws = (char*)d_ws;
  unsigned short* zb = (unsigned short*)ws;            // 16 MB bf16 z
  size_t off = (size_t)TWO_N * DIM * 2;
  float* part = (float*)(ws + off);                    // 8 MB: 256 x 8192 f32
  off += (size_t)256 * TWO_N * 4;
  float* pos = (float*)(ws + off);                     // 16 KB

  hipMemsetAsync(out, 0, sizeof(float), stream);
  prep_kernel<<<NN, 256, 0, stream>>>(z1, z2, zb, pos);
  lse_kernel<<<NBLK, 256, 0, stream>>>(zb, part);
  reduce_finalize_kernel<<<TWO_N / 256, 256, 0, stream>>>(part, pos, out);
}

// Round 14
// 128.205 us; speedup vs baseline: 1.1301x; 1.0216x over previous
//
#include <hip/hip_runtime.h>
#include <hip/hip_bf16.h>

// InfoNCE loss, N=4096, D=1024, TEMP=0.07.
// loss = mean_i( -pos_i + lse_i ), lse over sim rows with diagonal masked.
// Fixed-max LSE (rows unit-norm -> sim <= 1/T): partials order-independent.
// Symmetry via 256x256 tiles, upper triangle (J >= I), NBLK=528.
//
// R14: R10's m201-style 8-phase port with ALL sched_barrier(0) fences REMOVED
// (m141 precedent: order-pinning fences cost 1.7x; m201 template uses none).
// Phase body = exact m201: {ds_reads + 1 half-tile stage -> s_barrier ->
// asm lgkmcnt(0) -> setprio(1) -> 16 MFMA -> setprio(0) -> s_barrier}.
// Cross-phase safety: each wave's phase-p reads drain at its lgkmcnt(0)
// before BAR2(p), so phase-p+1 stages can't race them. Single counted
// vmcnt(4) gate per K-tile at ph4. Plane-store epilogue, Ji-bounded reduce.

typedef __attribute__((ext_vector_type(8))) short bf16x8;
typedef __attribute__((ext_vector_type(4))) float f32x4;

#define NN 4096
#define TWO_N 8192
#define DIM 1024
#define TEMP_INV 14.285714285714286f
#define EXP_SCALE 20.609929155566303f /* log2(e)/0.07 */
#define NTILE 32  /* 8192/256 */
#define NBLK 528  /* 32*33/2; 528 % 8 == 0 -> bijective XCD swizzle */

#define GLD16(g, l)                                                          \
  __builtin_amdgcn_global_load_lds(                                          \
      (const __attribute__((address_space(1))) void*)(g),                    \
      (__attribute__((address_space(3))) void*)(l), 16, 0, 0)

__device__ __forceinline__ unsigned short f2bf(float f) {
  unsigned int u = __float_as_uint(f);
  u += 0x7fffu + ((u >> 16) & 1u);  // RNE
  return (unsigned short)(u >> 16);
}

// Fused: fp32->bf16 cast of z=[z1;z2] AND pos[row]=dot(z1,z2)/T (one 32MB read).
__global__ __launch_bounds__(256) void prep_kernel(
    const float* __restrict__ z1, const float* __restrict__ z2,
    unsigned short* __restrict__ zb, float* __restrict__ pos) {
  const int row = blockIdx.x, t = threadIdx.x;
  float4 a = ((const float4*)(z1 + (size_t)row * DIM))[t];
  float4 b = ((const float4*)(z2 + (size_t)row * DIM))[t];
  ushort4 ua = {f2bf(a.x), f2bf(a.y), f2bf(a.z), f2bf(a.w)};
  ushort4 ub = {f2bf(b.x), f2bf(b.y), f2bf(b.z), f2bf(b.w)};
  ((ushort4*)(zb + (size_t)row * DIM))[t] = ua;
  ((ushort4*)(zb + (size_t)(NN + row) * DIM))[t] = ub;
  float s = a.x * b.x + a.y * b.y + a.z * b.z + a.w * b.w;
#pragma unroll
  for (int off = 1; off < 64; off <<= 1) s += __shfl_xor(s, off);
  __shared__ float tmp[4];
  if ((t & 63) == 0) tmp[t >> 6] = s;
  __syncthreads();
  if (t == 0) pos[row] = (tmp[0] + tmp[1] + tmp[2] + tmp[3]) * TEMP_INV;
}

__global__ __launch_bounds__(512, 2) void lse_kernel(
    const unsigned short* __restrict__ zb, float* __restrict__ part) {
  extern __shared__ unsigned char lds[];  // 2 bufs x (A 32KB + B 32KB) = 128 KiB
  // ---- tile decode: XCD swizzle -> upper-tri (I, J), J >= I ----
  int u = ((int)blockIdx.x & 7) * (NBLK / 8) + ((int)blockIdx.x >> 3);
  int I = 0, rem = u;
  while (rem >= NTILE - I) { rem -= NTILE - I; ++I; }
  const int J = I + rem;
  const int rowA0 = I * 256, colB0 = J * 256;
  const bool diag = (I == J);

  const int t = threadIdx.x;
  const int wave = t >> 6, lane = t & 63;
  const int wm = wave >> 2, wn = wave & 3;  // 2M x 4N waves, 128x64 out each
  const int lo = lane & 15, hi = lane >> 4;

  // ---- staging: half-tile = 128 rows x 64 k (16 KB), 2 gld16/thread.
  // Chunk c = l*512 + t: row r=c>>3, phys 16B-group p=c&7 holds logical
  // lg = p ^ (r&7) (inverse of read-side XOR); rows r and r+64 via +8192.
  const int r0 = t >> 3;
  const int lgrp = (t & 7) ^ (r0 & 7);
  const size_t soff = (size_t)r0 * DIM + lgrp * 8;  // shorts
  const unsigned short* gA = zb + (size_t)rowA0 * DIM + soff;
  const unsigned short* gB = zb + (size_t)colB0 * DIM + soff;
  const int dst0 = wave * 1024;  // byte offset inside a half-tile region

  // ---- read-side swizzled offsets (bytes). Row stride 128 B; 16B-group
  // g = kk*4 + hi, phys = g ^ (row&7) = g ^ (lo&7). ----
  const int gp0 = ((0 + hi) ^ (lo & 7)) * 16;  // kk=0
  const int gp1 = ((4 + hi) ^ (lo & 7)) * 16;  // kk=1
  const int abase = (wm * 128 + lo) * 128;         // within A region
  const int bbase = 32768 + (wn * 64 + lo) * 128;  // within B region

  f32x4 acc[8][4];
#pragma unroll
  for (int m = 0; m < 8; ++m)
#pragma unroll
    for (int n = 0; n < 4; ++n) acc[m][n] = (f32x4){0.f, 0.f, 0.f, 0.f};

#define BUFP(b_) (lds + (b_) * 65536)
#define STG_A(b_, h_, kt_)                                                    \
  {                                                                           \
    const unsigned short* s_ = gA + (size_t)((h_) * 128) * DIM + ((kt_) & 15) * 64; \
    unsigned char* d_ = BUFP(b_) + (h_) * 16384 + dst0;                       \
    GLD16(s_, d_);                                                            \
    GLD16(s_ + (size_t)64 * DIM, d_ + 8192);                                  \
  }
#define STG_B(b_, h_, kt_)                                                    \
  {                                                                           \
    const unsigned short* s_ = gB + (size_t)((h_) * 128) * DIM + ((kt_) & 15) * 64; \
    unsigned char* d_ = BUFP(b_) + 32768 + (h_) * 16384 + dst0;               \
    GLD16(s_, d_);                                                            \
    GLD16(s_ + (size_t)64 * DIM, d_ + 8192);                                  \
  }
#define RD_A(AF, b_, mlo_, gp_)                                               \
  {                                                                           \
    const unsigned char* p_ = BUFP(b_) + abase + (gp_);                       \
    _Pragma("unroll") for (int i = 0; i < 4; ++i)                             \
        AF[i] = *(const bf16x8*)(p_ + ((mlo_) + i) * 2048);                   \
  }
#define RD_B(BF, b_, gp_)                                                     \
  {                                                                           \
    const unsigned char* p_ = BUFP(b_) + bbase + (gp_);                       \
    _Pragma("unroll") for (int i = 0; i < 4; ++i)                             \
        BF[i] = *(const bf16x8*)(p_ + i * 2048);                              \
  }
#define MFMA16(mlo_, AF, BF)                                                  \
  __builtin_amdgcn_s_setprio(1);                                              \
  _Pragma("unroll") for (int i = 0; i < 4; ++i)                               \
    _Pragma("unroll") for (int n = 0; n < 4; ++n)                             \
        acc[(mlo_) + i][n] = __builtin_amdgcn_mfma_f32_16x16x32_bf16(         \
            AF[i], BF[n], acc[(mlo_) + i][n], 0, 0, 0);                       \
  __builtin_amdgcn_s_setprio(0);
#define BAR __builtin_amdgcn_s_barrier()
#define LGKM0 asm volatile("s_waitcnt lgkmcnt(0)" ::: "memory")

  // GROUP(b_, t_): 4 phases on K-tile t_ from buf b_. NO sched_barriers.
  // Stage plan: (t+1).a0 @ph1, (t+1).a1 @ph2 -> buf ~b; (t+2).b0+b1 @ph4
  // -> buf b (B-region reads end at ph3, drained by ph3's LGKM0 + BAR).
  // Gate: vmcnt(4) at end of ph4 = keep (t+2).b* in flight, drain (t+1).*.
#define GROUP(b_, t_)                                                         \
  {                                                                           \
    bf16x8 af[4], bf[4];                                                      \
    /* ph1: m0-3 x kk0 */                                                     \
    RD_A(af, b_, 0, gp0); RD_B(bf, b_, gp0);                                  \
    STG_A(1 - (b_), 0, (t_) + 1);                                             \
    BAR; LGKM0;                                                               \
    MFMA16(0, af, bf);                                                        \
    BAR;                                                                      \
    /* ph2: m4-7 x kk0 (B regs reused) */                                     \
    RD_A(af, b_, 4, gp0);                                                     \
    STG_A(1 - (b_), 1, (t_) + 1);                                             \
    BAR; LGKM0;                                                               \
    MFMA16(4, af, bf);                                                        \
    BAR;                                                                      \
    /* ph3: m0-3 x kk1 */                                                     \
    RD_A(af, b_, 0, gp1); RD_B(bf, b_, gp1);                                  \
    BAR; LGKM0;                                                               \
    MFMA16(0, af, bf);                                                        \
    BAR;                                                                      \
    /* ph4: m4-7 x kk1; stage next-next B halves; counted gate */             \
    RD_A(af, b_, 4, gp1);                                                     \
    STG_B(b_, 0, (t_) + 2); STG_B(b_, 1, (t_) + 2);                           \
    BAR; LGKM0;                                                               \
    MFMA16(4, af, bf);                                                        \
    asm volatile("s_waitcnt vmcnt(4)" ::: "memory");                          \
    BAR;                                                                      \
  }

  // prologue: tile 0 full -> buf0; tile 1 B-halves -> buf1; gate tile 0.
  STG_A(0, 0, 0); STG_A(0, 1, 0); STG_B(0, 0, 0); STG_B(0, 1, 0);
  STG_B(1, 0, 1); STG_B(1, 1, 1);
  asm volatile("s_waitcnt vmcnt(4)" ::: "memory");
  BAR;

#pragma unroll 1
  for (int tt = 0; tt < 16; tt += 2) {
    GROUP(0, tt);
    GROUP(1, tt + 1);
  }
  asm volatile("s_waitcnt vmcnt(0) lgkmcnt(0)" ::: "memory");  // drain dummies

  // ---- epilogue: e=exp((dot-1)/T), diag masked; row/col partial sums ----
  // NO atomics: plane stores. Row partials keyed (J, wn) -> planes 0..127;
  // col partials keyed (I, wm) -> planes 128..191. Disjoint by construction.
  float* rplane = part + (size_t)(4 * J + wn) * TWO_N;
  float* cplane = part + (size_t)(128 + 2 * I + wm) * TWO_N;
  float csum[4] = {0.f, 0.f, 0.f, 0.f};
#pragma unroll
  for (int m = 0; m < 8; ++m) {
#pragma unroll
    for (int r = 0; r < 4; ++r) {
      const int grow = rowA0 + wm * 128 + m * 16 + hi * 4 + r;  // row=(lane>>4)*4+reg
      float s = 0.f;
#pragma unroll
      for (int n = 0; n < 4; ++n) {
        const int gcol = colB0 + wn * 64 + n * 16 + lo;         // col=lane&15
        float e = exp2f((acc[m][n][r] - 1.0f) * EXP_SCALE);
        if (grow == gcol) e = 0.f;  // mask self-similarity (diag tiles)
        s += e;
        csum[n] += e;
      }
      s += __shfl_xor(s, 1); s += __shfl_xor(s, 2);
      s += __shfl_xor(s, 4); s += __shfl_xor(s, 8);
      if (lo == 0) rplane[grow] = s;  // 4 lanes x 32 (m,r) = 128 rows/wave
    }
  }
  if (!diag) {  // off-diagonal tiles feed transposed rows via col sums
#pragma unroll
    for (int n = 0; n < 4; ++n) {
      float s = csum[n];
      s += __shfl_xor(s, 16); s += __shfl_xor(s, 32);
      if (hi == 0) cplane[colB0 + wn * 64 + n * 16 + lo] = s;  // 16 lanes x 4n
    }
  }
#undef GROUP
#undef MFMA16
#undef RD_A
#undef RD_B
#undef STG_A
#undef STG_B
#undef BUFP
#undef BAR
#undef LGKM0
}

// Fold only provably-written plane entries -> per-row term -> mean.
// Row i (Ii = i>>8): row-planes 4J+wn written iff J >= Ii; col-planes
// 128+2I+wm iff I < Ii. Stale bytes never read -> no part memset.
__global__ __launch_bounds__(256) void reduce_finalize_kernel(
    const float* __restrict__ part, const float* __restrict__ pos,
    float* __restrict__ out) {
  const int i = blockIdx.x * 256 + threadIdx.x;
  const int Ii = i >> 8;
  float s = 0.f;
  for (int J = Ii; J < NTILE; ++J) {
    const float* p = part + (size_t)(4 * J) * TWO_N + i;
    s += p[0] + p[TWO_N] + p[2 * (size_t)TWO_N] + p[3 * (size_t)TWO_N];
  }
  for (int I2 = 0; I2 < Ii; ++I2) {
    const float* p = part + (size_t)(128 + 2 * I2) * TWO_N + i;
    s += p[0] + p[TWO_N];
  }
  float term = TEMP_INV + logf(s) - pos[i & (NN - 1)];
#pragma unroll
  for (int off = 1; off < 64; off <<= 1) term += __shfl_xor(term, off);
  __shared__ float tmp[4];
  const int t = threadIdx.x;
  if ((t & 63) == 0) tmp[t >> 6] = term;
  __syncthreads();
  if (t == 0)
    atomicAdd(out, (tmp[0] + tmp[1] + tmp[2] + tmp[3]) * (1.0f / (float)TWO_N));
}

extern "C" void kernel_launch(void* const* d_in, const int* in_sizes, int n_in,
                              void* d_out, int out_size, void* d_ws, size_t ws_size,
                              hipStream_t stream) {
  const float* z1 = (const float*)d_in[0];
  const float* z2 = (const float*)d_in[1];
  float* out = (float*)d_out;

  char* ws = (char*)d_ws;
  unsigned short* zb = (unsigned short*)ws;            // 16 MB bf16 z
  size_t off = (size_t)TWO_N * DIM * 2;
  float* part = (float*)(ws + off);                    // 6 MB: 192 x 8192 f32
  off += (size_t)192 * TWO_N * 4;
  float* pos = (float*)(ws + off);                     // 16 KB

  hipMemsetAsync(out, 0, sizeof(float), stream);
  prep_kernel<<<NN, 256, 0, stream>>>(z1, z2, zb, pos);
  lse_kernel<<<NBLK, 512, 131072, stream>>>(zb, part);
  reduce_finalize_kernel<<<TWO_N / 256, 256, 0, stream>>>(part, pos, out);
}

// Round 15
// 127.976 us; speedup vs baseline: 1.1321x; 1.0018x over previous
//
#include <hip/hip_runtime.h>
#include <hip/hip_bf16.h>

// InfoNCE loss, N=4096, D=1024, TEMP=0.07.
// loss = mean_i( -pos_i + lse_i ), lse over sim rows with diagonal masked.
// Fixed-max LSE (rows unit-norm -> sim <= 1/T): partials order-independent.
// Symmetry via 256x256 tiles, upper triangle (J >= I), NBLK=528.
//
// R14: R10's m201-style 8-phase port with ALL sched_barrier(0) fences REMOVED
// (m141 precedent: order-pinning fences cost 1.7x; m201 template uses none).
// Phase body = exact m201: {ds_reads + 1 half-tile stage -> s_barrier ->
// asm lgkmcnt(0) -> setprio(1) -> 16 MFMA -> setprio(0) -> s_barrier}.
// Cross-phase safety: each wave's phase-p reads drain at its lgkmcnt(0)
// before BAR2(p), so phase-p+1 stages can't race them. Single counted
// vmcnt(4) gate per K-tile at ph4. Plane-store epilogue, Ji-bounded reduce.

typedef __attribute__((ext_vector_type(8))) short bf16x8;
typedef __attribute__((ext_vector_type(4))) float f32x4;

#define NN 4096
#define TWO_N 8192
#define DIM 1024
#define TEMP_INV 14.285714285714286f
#define EXP_SCALE 20.609929155566303f /* log2(e)/0.07 */
#define NTILE 32  /* 8192/256 */
#define NBLK 528  /* 32*33/2; 528 % 8 == 0 -> bijective XCD swizzle */

#define GLD16(g, l)                                                          \
  __builtin_amdgcn_global_load_lds(                                          \
      (const __attribute__((address_space(1))) void*)(g),                    \
      (__attribute__((address_space(3))) void*)(l), 16, 0, 0)

__device__ __forceinline__ unsigned short f2bf(float f) {
  unsigned int u = __float_as_uint(f);
  u += 0x7fffu + ((u >> 16) & 1u);  // RNE
  return (unsigned short)(u >> 16);
}

// Fused: fp32->bf16 cast of z=[z1;z2] AND pos[row]=dot(z1,z2)/T (one 32MB read).
__global__ __launch_bounds__(256) void prep_kernel(
    const float* __restrict__ z1, const float* __restrict__ z2,
    unsigned short* __restrict__ zb, float* __restrict__ pos) {
  const int row = blockIdx.x, t = threadIdx.x;
  float4 a = ((const float4*)(z1 + (size_t)row * DIM))[t];
  float4 b = ((const float4*)(z2 + (size_t)row * DIM))[t];
  ushort4 ua = {f2bf(a.x), f2bf(a.y), f2bf(a.z), f2bf(a.w)};
  ushort4 ub = {f2bf(b.x), f2bf(b.y), f2bf(b.z), f2bf(b.w)};
  ((ushort4*)(zb + (size_t)row * DIM))[t] = ua;
  ((ushort4*)(zb + (size_t)(NN + row) * DIM))[t] = ub;
  float s = a.x * b.x + a.y * b.y + a.z * b.z + a.w * b.w;
#pragma unroll
  for (int off = 1; off < 64; off <<= 1) s += __shfl_xor(s, off);
  __shared__ float tmp[4];
  if ((t & 63) == 0) tmp[t >> 6] = s;
  __syncthreads();
  if (t == 0) pos[row] = (tmp[0] + tmp[1] + tmp[2] + tmp[3]) * TEMP_INV;
}

__global__ __launch_bounds__(512, 2) void lse_kernel(
    const unsigned short* __restrict__ zb, float* __restrict__ part) {
  extern __shared__ unsigned char lds[];  // 2 bufs x (A 32KB + B 32KB) = 128 KiB
  // ---- tile decode: XCD swizzle -> upper-tri (I, J), J >= I ----
  int u = ((int)blockIdx.x & 7) * (NBLK / 8) + ((int)blockIdx.x >> 3);
  int I = 0, rem = u;
  while (rem >= NTILE - I) { rem -= NTILE - I; ++I; }
  const int J = I + rem;
  const int rowA0 = I * 256, colB0 = J * 256;
  const bool diag = (I == J);

  const int t = threadIdx.x;
  const int wave = t >> 6, lane = t & 63;
  const int wm = wave >> 2, wn = wave & 3;  // 2M x 4N waves, 128x64 out each
  const int lo = lane & 15, hi = lane >> 4;

  // ---- staging: half-tile = 128 rows x 64 k (16 KB), 2 gld16/thread.
  // Chunk c = l*512 + t: row r=c>>3, phys 16B-group p=c&7 holds logical
  // lg = p ^ (r&7) (inverse of read-side XOR); rows r and r+64 via +8192.
  const int r0 = t >> 3;
  const int lgrp = (t & 7) ^ (r0 & 7);
  const size_t soff = (size_t)r0 * DIM + lgrp * 8;  // shorts
  const unsigned short* gA = zb + (size_t)rowA0 * DIM + soff;
  const unsigned short* gB = zb + (size_t)colB0 * DIM + soff;
  const int dst0 = wave * 1024;  // byte offset inside a half-tile region

  // ---- read-side swizzled offsets (bytes). Row stride 128 B; 16B-group
  // g = kk*4 + hi, phys = g ^ (row&7) = g ^ (lo&7). ----
  const int gp0 = ((0 + hi) ^ (lo & 7)) * 16;  // kk=0
  const int gp1 = ((4 + hi) ^ (lo & 7)) * 16;  // kk=1
  const int abase = (wm * 128 + lo) * 128;         // within A region
  const int bbase = 32768 + (wn * 64 + lo) * 128;  // within B region

  f32x4 acc[8][4];
#pragma unroll
  for (int m = 0; m < 8; ++m)
#pragma unroll
    for (int n = 0; n < 4; ++n) acc[m][n] = (f32x4){0.f, 0.f, 0.f, 0.f};

#define BUFP(b_) (lds + (b_) * 65536)
#define STG_A(b_, h_, kt_)                                                    \
  {                                                                           \
    const unsigned short* s_ = gA + (size_t)((h_) * 128) * DIM + ((kt_) & 15) * 64; \
    unsigned char* d_ = BUFP(b_) + (h_) * 16384 + dst0;                       \
    GLD16(s_, d_);                                                            \
    GLD16(s_ + (size_t)64 * DIM, d_ + 8192);                                  \
  }
#define STG_B(b_, h_, kt_)                                                    \
  {                                                                           \
    const unsigned short* s_ = gB + (size_t)((h_) * 128) * DIM + ((kt_) & 15) * 64; \
    unsigned char* d_ = BUFP(b_) + 32768 + (h_) * 16384 + dst0;               \
    GLD16(s_, d_);                                                            \
    GLD16(s_ + (size_t)64 * DIM, d_ + 8192);                                  \
  }
#define RD_A(AF, b_, mlo_, gp_)                                               \
  {                                                                           \
    const unsigned char* p_ = BUFP(b_) + abase + (gp_);                       \
    _Pragma("unroll") for (int i = 0; i < 4; ++i)                             \
        AF[i] = *(const bf16x8*)(p_ + ((mlo_) + i) * 2048);                   \
  }
#define RD_B(BF, b_, gp_)                                                     \
  {                                                                           \
    const unsigned char* p_ = BUFP(b_) + bbase + (gp_);                       \
    _Pragma("unroll") for (int i = 0; i < 4; ++i)                             \
        BF[i] = *(const bf16x8*)(p_ + i * 2048);                              \
  }
#define MFMA16(mlo_, AF, BF)                                                  \
  __builtin_amdgcn_s_setprio(1);                                              \
  _Pragma("unroll") for (int i = 0; i < 4; ++i)                               \
    _Pragma("unroll") for (int n = 0; n < 4; ++n)                             \
        acc[(mlo_) + i][n] = __builtin_amdgcn_mfma_f32_16x16x32_bf16(         \
            AF[i], BF[n], acc[(mlo_) + i][n], 0, 0, 0);                       \
  __builtin_amdgcn_s_setprio(0);
#define BAR __builtin_amdgcn_s_barrier()
#define LGKM0 asm volatile("s_waitcnt lgkmcnt(0)" ::: "memory")

  // GROUP(b_, t_): 4 phases on K-tile t_ from buf b_. NO sched_barriers.
  // Stage plan: (t+1).a0 @ph1, (t+1).a1 @ph2 -> buf ~b; (t+2).b0+b1 @ph4
  // -> buf b (B-region reads end at ph3, drained by ph3's LGKM0 + BAR).
  // Gate: vmcnt(4) at end of ph4 = keep (t+2).b* in flight, drain (t+1).*.
#define GROUP(b_, t_)                                                         \
  {                                                                           \
    bf16x8 af[4], bf[4];                                                      \
    /* ph1: m0-3 x kk0 */                                                     \
    RD_A(af, b_, 0, gp0); RD_B(bf, b_, gp0);                                  \
    STG_A(1 - (b_), 0, (t_) + 1);                                             \
    BAR; LGKM0;                                                               \
    MFMA16(0, af, bf);                                                        \
    BAR;                                                                      \
    /* ph2: m4-7 x kk0 (B regs reused) */                                     \
    RD_A(af, b_, 4, gp0);                                                     \
    STG_A(1 - (b_), 1, (t_) + 1);                                             \
    BAR; LGKM0;                                                               \
    MFMA16(4, af, bf);                                                        \
    BAR;                                                                      \
    /* ph3: m0-3 x kk1 */                                                     \
    RD_A(af, b_, 0, gp1); RD_B(bf, b_, gp1);                                  \
    BAR; LGKM0;                                                               \
    MFMA16(0, af, bf);                                                        \
    BAR;                                                                      \
    /* ph4: m4-7 x kk1; stage next-next B halves; counted gate */             \
    RD_A(af, b_, 4, gp1);                                                     \
    STG_B(b_, 0, (t_) + 2); STG_B(b_, 1, (t_) + 2);                           \
    BAR; LGKM0;                                                               \
    MFMA16(4, af, bf);                                                        \
    asm volatile("s_waitcnt vmcnt(4)" ::: "memory");                          \
    BAR;                                                                      \
  }

  // prologue: tile 0 full -> buf0; tile 1 B-halves -> buf1; gate tile 0.
  STG_A(0, 0, 0); STG_A(0, 1, 0); STG_B(0, 0, 0); STG_B(0, 1, 0);
  STG_B(1, 0, 1); STG_B(1, 1, 1);
  asm volatile("s_waitcnt vmcnt(4)" ::: "memory");
  BAR;

#pragma unroll 1
  for (int tt = 0; tt < 16; tt += 2) {
    GROUP(0, tt);
    GROUP(1, tt + 1);
  }
  asm volatile("s_waitcnt vmcnt(0) lgkmcnt(0)" ::: "memory");  // drain dummies

  // ---- epilogue: e=exp((dot-1)/T), diag masked; row/col partial sums ----
  // NO atomics: plane stores. Row partials keyed (J, wn) -> planes 0..127;
  // col partials keyed (I, wm) -> planes 128..191. Disjoint by construction.
  float* rplane = part + (size_t)(4 * J + wn) * TWO_N;
  float* cplane = part + (size_t)(128 + 2 * I + wm) * TWO_N;
  float csum[4] = {0.f, 0.f, 0.f, 0.f};
#pragma unroll
  for (int m = 0; m < 8; ++m) {
#pragma unroll
    for (int r = 0; r < 4; ++r) {
      const int grow = rowA0 + wm * 128 + m * 16 + hi * 4 + r;  // row=(lane>>4)*4+reg
      float s = 0.f;
#pragma unroll
      for (int n = 0; n < 4; ++n) {
        const int gcol = colB0 + wn * 64 + n * 16 + lo;         // col=lane&15
        float e = exp2f((acc[m][n][r] - 1.0f) * EXP_SCALE);
        if (grow == gcol) e = 0.f;  // mask self-similarity (diag tiles)
        s += e;
        csum[n] += e;
      }
      s += __shfl_xor(s, 1); s += __shfl_xor(s, 2);
      s += __shfl_xor(s, 4); s += __shfl_xor(s, 8);
      if (lo == 0) rplane[grow] = s;  // 4 lanes x 32 (m,r) = 128 rows/wave
    }
  }
  if (!diag) {  // off-diagonal tiles feed transposed rows via col sums
#pragma unroll
    for (int n = 0; n < 4; ++n) {
      float s = csum[n];
      s += __shfl_xor(s, 16); s += __shfl_xor(s, 32);
      if (hi == 0) cplane[colB0 + wn * 64 + n * 16 + lo] = s;  // 16 lanes x 4n
    }
  }
#undef GROUP
#undef MFMA16
#undef RD_A
#undef RD_B
#undef STG_A
#undef STG_B
#undef BUFP
#undef BAR
#undef LGKM0
}

// Fold only provably-written plane entries -> per-row term -> mean.
// Row i (Ii = i>>8): row-planes 4J+wn written iff J >= Ii; col-planes
// 128+2I+wm iff I < Ii. Stale bytes never read -> no part memset.
__global__ __launch_bounds__(256) void reduce_finalize_kernel(
    const float* __restrict__ part, const float* __restrict__ pos,
    float* __restrict__ out) {
  const int i = blockIdx.x * 256 + threadIdx.x;
  const int Ii = i >> 8;
  float s = 0.f;
  for (int J = Ii; J < NTILE; ++J) {
    const float* p = part + (size_t)(4 * J) * TWO_N + i;
    s += p[0] + p[TWO_N] + p[2 * (size_t)TWO_N] + p[3 * (size_t)TWO_N];
  }
  for (int I2 = 0; I2 < Ii; ++I2) {
    const float* p = part + (size_t)(128 + 2 * I2) * TWO_N + i;
    s += p[0] + p[TWO_N];
  }
  float term = TEMP_INV + logf(s) - pos[i & (NN - 1)];
#pragma unroll
  for (int off = 1; off < 64; off <<= 1) term += __shfl_xor(term, off);
  __shared__ float tmp[4];
  const int t = threadIdx.x;
  if ((t & 63) == 0) tmp[t >> 6] = term;
  __syncthreads();
  if (t == 0)
    atomicAdd(out, (tmp[0] + tmp[1] + tmp[2] + tmp[3]) * (1.0f / (float)TWO_N));
}

extern "C" void kernel_launch(void* const* d_in, const int* in_sizes, int n_in,
                              void* d_out, int out_size, void* d_ws, size_t ws_size,
                              hipStream_t stream) {
  const float* z1 = (const float*)d_in[0];
  const float* z2 = (const float*)d_in[1];
  float* out = (float*)d_out;

  char* ws = (char*)d_ws;
  unsigned short* zb = (unsigned short*)ws;            // 16 MB bf16 z
  size_t off = (size_t)TWO_N * DIM * 2;
  float* part = (float*)(ws + off);                    // 6 MB: 192 x 8192 f32
  off += (size_t)192 * TWO_N * 4;
  float* pos = (float*)(ws + off);                     // 16 KB

  hipMemsetAsync(out, 0, sizeof(float), stream);
  prep_kernel<<<NN, 256, 0, stream>>>(z1, z2, zb, pos);
  lse_kernel<<<NBLK, 512, 131072, stream>>>(zb, part);
  reduce_finalize_kernel<<<TWO_N / 256, 256, 0, stream>>>(part, pos, out);
}